// Round 5
// baseline (132.799 us; speedup 1.0000x reference)
//
#include <hip/hip_runtime.h>

// Problem constants (fixed by reference setup_inputs)
#define B_N 8192
#define D_N 256
#define N_N 2048
#define K_N 512
#define T_N 8

using short8  = __attribute__((ext_vector_type(8))) short;
using floatx4 = __attribute__((ext_vector_type(4))) float;

// ---------------------------------------------------------------------------
// Workspace layout (float units):
//  cb        = ws + 0      [8192]
//  nn2       = ws + 8192   [2048]
//  fn2       = ws + 10240  [512]
//  jt_part   = ws + 10752  [2048]   (per prep-block jt partials)
//  msum_part = ws + 12800  [32]
//  acc       = ws + 12832  [2]      (ju_sum, ortho_sum) -- init'd by prep
//  cnt       = (int*)(ws + 12834)   -- arrival counter   -- init'd by prep
//  vhat_bf   = (ushort*)(ws + 12848)  [8192*256]  (16B aligned: 12848*4%16==0)
//  neg_bf    = vhat_bf + 8192*256     [2048*256]
//  F_bf      = neg_bf + 2048*256      [512*256]
// ---------------------------------------------------------------------------

// butterfly reduce: ALL lanes end with the wave sum
__device__ __forceinline__ float wave_reduce_sum(float x) {
  #pragma unroll
  for (int off = 32; off > 0; off >>= 1) x += __shfl_xor(x, off, 64);
  return x;
}

__device__ __forceinline__ unsigned int f2bf(float x) {
  unsigned u = __float_as_uint(x);
  return (u + 0x7fffu + ((u >> 16) & 1u)) >> 16;
}

__device__ __forceinline__ unsigned int pack2bf(float x, float y) {
  return f2bf(x) | (f2bf(y) << 16);
}

// async global->LDS, 16 bytes per lane; LDS dest is wave-uniform base + lane*16
__device__ __forceinline__ void gload16(const unsigned short* g, unsigned short* l) {
  __builtin_amdgcn_global_load_lds(
      (const __attribute__((address_space(1))) unsigned int*)g,
      (__attribute__((address_space(3))) unsigned int*)l, 16, 0, 0);
}

// compare-swap keeping (val,idx) pairs together
#define CSWAP(a, b)                                              \
  {                                                              \
    bool sw_ = sv[a] > sv[b];                                    \
    float tv_ = sw_ ? sv[a] : sv[b];                             \
    sv[a] = sw_ ? sv[b] : sv[a];                                 \
    sv[b] = tv_;                                                 \
    int ti_ = sw_ ? si[a] : si[b];                               \
    si[a] = sw_ ? si[b] : si[a];                                 \
    si[b] = ti_;                                                 \
  }

// --- prep: stats + bf16 conversion + bottom-8 selection + FUSED jt ----------
// one row per wave; rows [0,B)=vhat(+v,+g-selection,+jt), [B,B+N)=neg, rest=F
__global__ __launch_bounds__(256) void prep_kernel(
    const float* __restrict__ v, const float* __restrict__ vhat,
    const float* __restrict__ neg, const float* __restrict__ F,
    const float* __restrict__ g, const int* __restrict__ mask,
    unsigned short* __restrict__ vhat_bf, unsigned short* __restrict__ neg_bf,
    unsigned short* __restrict__ F_bf,
    float* __restrict__ cb, float* __restrict__ nn2, float* __restrict__ fn2,
    float* __restrict__ jt_part, float* __restrict__ msum_part,
    float* __restrict__ acc, int* __restrict__ cnt) {
  int lane = threadIdx.x & 63;
  int wave = threadIdx.x >> 6;
  int row = (blockIdx.x << 2) + wave;
  __shared__ float mred[4];
  __shared__ float jred[4];
  // re-init main's accumulators each launch (workspace is poisoned between runs)
  if (blockIdx.x == 0 && threadIdx.x == 0) {
    acc[0] = 0.0f; acc[1] = 0.0f; *cnt = 0;
  }
  // msum strips: blocks 0..31 each sum 256 mask entries (block-uniform branch)
  if (blockIdx.x < 32) {
    float m = (mask[blockIdx.x * 256 + threadIdx.x] != 0) ? 1.0f : 0.0f;
    m = wave_reduce_sum(m);
    if (lane == 0) mred[wave] = m;
    __syncthreads();
    if (threadIdx.x == 0)
      msum_part[blockIdx.x] = mred[0] + mred[1] + mred[2] + mred[3];
  }
  if (row < B_N) {
    const float4 a = *(const float4*)(vhat + (size_t)row * D_N + lane * 4);
    const float4 b = *(const float4*)(v + (size_t)row * D_N + lane * 4);
    float dx = a.x - b.x, dy = a.y - b.y, dz = a.z - b.z, dw = a.w - b.w;
    float t = dx * dx + dy * dy + dz * dz + dw * dw;
    float n = a.x * a.x + a.y * a.y + a.z * a.z + a.w * a.w;
    uint2 p;
    p.x = pack2bf(a.x, a.y);
    p.y = pack2bf(a.z, a.w);
    *(uint2*)(vhat_bf + (size_t)row * D_N + lane * 4) = p;
    t = wave_reduce_sum(t);  // td, all lanes
    n = wave_reduce_sum(n);  // vn2, all lanes
    if (lane == 0) cb[row] = 1.0f + t - n;
    // ---- bottom-8-of-512 selection on g[row] ----
    const float* grow = g + (size_t)row * K_N;
    float sv[8];
    int si[8];
    {
      float4 g0 = *(const float4*)(grow + lane * 8);
      float4 g1 = *(const float4*)(grow + lane * 8 + 4);
      sv[0] = g0.x; sv[1] = g0.y; sv[2] = g0.z; sv[3] = g0.w;
      sv[4] = g1.x; sv[5] = g1.y; sv[6] = g1.z; sv[7] = g1.w;
      #pragma unroll
      for (int j = 0; j < 8; ++j) si[j] = lane * 8 + j;
    }
    // Batcher odd-even mergesort, n=8 (19 comparators) -> ascending
    CSWAP(0,1) CSWAP(2,3) CSWAP(4,5) CSWAP(6,7)
    CSWAP(0,2) CSWAP(1,3) CSWAP(4,6) CSWAP(5,7)
    CSWAP(1,2) CSWAP(5,6)
    CSWAP(0,4) CSWAP(1,5) CSWAP(2,6) CSWAP(3,7)
    CSWAP(2,4) CSWAP(3,5)
    CSWAP(1,2) CSWAP(3,4) CSWAP(5,6)
    // 6 butterfly merge rounds: keep lowest 8 of (mine ++ partner)
    #pragma unroll
    for (int rr = 0; rr < 6; ++rr) {
      const int msk = 1 << rr;
      float pv[8];
      int pi[8];
      #pragma unroll
      for (int j = 0; j < 8; ++j) {
        pv[j] = __shfl_xor(sv[j], msk, 64);
        pi[j] = __shfl_xor(si[j], msk, 64);
      }
      float cv[8];
      int ci[8];
      #pragma unroll
      for (int j = 0; j < 8; ++j) {
        bool mine = sv[j] <= pv[7 - j];
        cv[j] = mine ? sv[j] : pv[7 - j];
        ci[j] = mine ? si[j] : pi[7 - j];
      }
      #pragma unroll
      for (int j = 0; j < 8; ++j) { sv[j] = cv[j]; si[j] = ci[j]; }
      // bitonic -> sorted (distances 4,2,1)
      CSWAP(0,4) CSWAP(1,5) CSWAP(2,6) CSWAP(3,7)
      CSWAP(0,2) CSWAP(1,3) CSWAP(4,6) CSWAP(5,7)
      CSWAP(0,1) CSWAP(2,3) CSWAP(4,5) CSWAP(6,7)
    }
    // every lane now holds the global bottom-8 (sorted, identical across lanes)
    // ---- fused jt: 8 gathered f32 dot products (F is L2-resident) ----
    float4 fr8[8];
    #pragma unroll
    for (int t8 = 0; t8 < T_N; ++t8) {
      int idx = __builtin_amdgcn_readfirstlane(si[t8]);
      fr8[t8] = *(const float4*)(F + (size_t)idx * D_N + lane * 4);
    }
    float gsum = 1e-10f;
    #pragma unroll
    for (int t8 = 0; t8 < T_N; ++t8) gsum += sv[t8];
    float base = t - n;  // td - vn2, all lanes
    float jts = 0.0f;
    #pragma unroll
    for (int t8 = 0; t8 < T_N; ++t8) {
      float4 f = fr8[t8];
      // s = 2*<vhat,F_idx> - ||F_idx||^2 ; then term = mt + td - vn2 + s
      float s = 2.0f * (a.x * f.x + a.y * f.y + a.z * f.z + a.w * f.w)
              - (f.x * f.x + f.y * f.y + f.z * f.z + f.w * f.w);
      s = wave_reduce_sum(s);
      float gt = sv[t8] / gsum;
      float mt = 1.0f - gt;
      mt *= mt;
      jts += fmaxf(mt + base + s, 0.0f);
    }
    float mf = (mask[row] != 0) ? 1.0f : 0.0f;
    if (lane == 0) jred[wave] = jts * mf;
    __syncthreads();
    if (threadIdx.x == 0)
      jt_part[blockIdx.x] = jred[0] + jred[1] + jred[2] + jred[3];
  } else if (row < B_N + N_N) {
    int r = row - B_N;
    const float4 a = *(const float4*)(neg + (size_t)r * D_N + lane * 4);
    float n = a.x * a.x + a.y * a.y + a.z * a.z + a.w * a.w;
    uint2 p;
    p.x = pack2bf(a.x, a.y);
    p.y = pack2bf(a.z, a.w);
    *(uint2*)(neg_bf + (size_t)r * D_N + lane * 4) = p;
    n = wave_reduce_sum(n);
    if (lane == 0) nn2[r] = n;
  } else {
    int r = row - (B_N + N_N);
    const float4 a = *(const float4*)(F + (size_t)r * D_N + lane * 4);
    float n = a.x * a.x + a.y * a.y + a.z * a.z + a.w * a.w;
    uint2 p;
    p.x = pack2bf(a.x, a.y);
    p.y = pack2bf(a.z, a.w);
    *(uint2*)(F_bf + (size_t)r * D_N + lane * 4) = p;
    n = wave_reduce_sum(n);
    if (lane == 0) fn2[r] = n;
  }
}

// --- main: ortho tiles [0,10) (upper triangle) | ju tiles [10,1034) ---------
// R2 K-loop (best measured; dbuf/BK=64 both failed to beat it). Finalize is
// fused FENCE-FREE: per-block atomicAdd into acc[seg], completion forced by
// consuming the returned value (compiler emits vmcnt wait) BEFORE bumping the
// arrival counter; the last-arriving block reads acc atomically and computes
// the output. No __threadfence (R1 showed per-block fences cost ~35 us).
__global__ __launch_bounds__(256) void main_kernel(
    const unsigned short* __restrict__ vhat_bf, const unsigned short* __restrict__ neg_bf,
    const unsigned short* __restrict__ F_bf,
    const float* __restrict__ cb, const float* __restrict__ nn2,
    const float* __restrict__ fn2, const int* __restrict__ mask,
    const float* __restrict__ jt_part, const float* __restrict__ msum_part,
    float* __restrict__ acc, int* __restrict__ cnt, float* __restrict__ out) {
  __shared__ __align__(16) unsigned char smem[16384];
  __shared__ int lastFlag;
  const int bx = blockIdx.x;
  const int tid = threadIdx.x;
  const int lane = tid & 63;
  const int wave = tid >> 6;

  unsigned short* AsU = (unsigned short*)smem;  // 128 rows x 32 k (bf16)
  unsigned short* BsU = AsU + 4096;
  int r0, c0;
  const unsigned short *Abase, *Bbase;
  int seg;          // 0=ju 1=ortho
  float wgt = 1.0f;
  if (bx < 10) {
    // ortho first (small); upper-triangle tile (ti<=tj), off-diag counted x2
    seg = 1;
    int o = bx;
    int ti = (o < 4) ? 0 : (o < 7) ? 1 : (o < 9) ? 2 : 3;
    int tj = (o < 4) ? o : (o < 7) ? o - 3 : (o < 9) ? o - 5 : 3;
    r0 = ti * 128;
    c0 = tj * 128;
    wgt = (ti == tj) ? 1.0f : 2.0f;
    Abase = F_bf;
    Bbase = F_bf;
  } else {
    seg = 0;
    int o = bx - 10;
    // XCD swizzle (1024 % 8 == 0, bijective): XCD x owns contiguous lo-range
    int lo = (o & 7) * 128 + (o >> 3);
    r0 = (lo >> 4) * 128;
    c0 = (lo & 15) * 128;
    Abase = vhat_bf;
    Bbase = neg_bf;
  }
  const int wx = wave & 1, wy = wave >> 1;

  // staging: LDS slot (r, c_slot) holds global 16B-chunk c_g = c_slot ^ ((r>>1)&3)
  const int c_slot = lane & 3;
  const int rA0 = wave * 32 + (lane >> 2);
  const int rA1 = rA0 + 16;
  const int cg0 = c_slot ^ ((rA0 >> 1) & 3);
  const int cg1 = c_slot ^ ((rA1 >> 1) & 3);
  const unsigned short* gA0 = Abase + (size_t)(r0 + rA0) * D_N + cg0 * 8;
  const unsigned short* gA1 = Abase + (size_t)(r0 + rA1) * D_N + cg1 * 8;
  const unsigned short* gB0 = Bbase + (size_t)(c0 + rA0) * D_N + cg0 * 8;
  const unsigned short* gB1 = Bbase + (size_t)(c0 + rA1) * D_N + cg1 * 8;
  unsigned short* lA0 = AsU + wave * 1024 + lane * 8;
  unsigned short* lA1 = lA0 + 512;
  unsigned short* lB0 = BsU + wave * 1024 + lane * 8;
  unsigned short* lB1 = lB0 + 512;

  // fragment LDS offsets (constant over k-loop)
  const int fr = lane & 15;
  const int fc = lane >> 4;
  int aoff[4], boff[4];
  #pragma unroll
  for (int i = 0; i < 4; ++i) {
    int ra = wy * 64 + i * 16 + fr;
    aoff[i] = ra * 32 + (fc ^ ((ra >> 1) & 3)) * 8;
    int rb = wx * 64 + i * 16 + fr;
    boff[i] = rb * 32 + (fc ^ ((rb >> 1) & 3)) * 8;
  }

  floatx4 acc4[4][4];
  #pragma unroll
  for (int i = 0; i < 4; ++i)
    #pragma unroll
    for (int j = 0; j < 4; ++j)
      acc4[i][j] = floatx4{0.0f, 0.0f, 0.0f, 0.0f};

  for (int k0 = 0; k0 < D_N; k0 += 32) {
    __syncthreads();
    gload16(gA0 + k0, lA0);
    gload16(gA1 + k0, lA1);
    gload16(gB0 + k0, lB0);
    gload16(gB1 + k0, lB1);
    __syncthreads();
    short8 af[4], bfv[4];
    #pragma unroll
    for (int i = 0; i < 4; ++i) af[i] = *(const short8*)(AsU + aoff[i]);
    #pragma unroll
    for (int j = 0; j < 4; ++j) bfv[j] = *(const short8*)(BsU + boff[j]);
    #pragma unroll
    for (int i = 0; i < 4; ++i)
      #pragma unroll
      for (int j = 0; j < 4; ++j)
        acc4[i][j] = __builtin_amdgcn_mfma_f32_16x16x32_bf16(af[i], bfv[j], acc4[i][j], 0, 0, 0);
  }

  // epilogue: C/D layout col=lane&15 (j), row=(lane>>4)*4+reg (i)
  float lsum = 0.0f;
  if (seg == 0) {
    float nns[4];
    #pragma unroll
    for (int j = 0; j < 4; ++j)
      nns[j] = nn2[c0 + wx * 64 + j * 16 + (lane & 15)];
    #pragma unroll
    for (int i = 0; i < 4; ++i) {
      #pragma unroll
      for (int r = 0; r < 4; ++r) {
        int b = r0 + wy * 64 + i * 16 + (lane >> 4) * 4 + r;
        float cbb = cb[b];
        float mf = (mask[b] != 0) ? 1.0f : 0.0f;
        float rs = 0.0f;
        #pragma unroll
        for (int j = 0; j < 4; ++j) {
          float val = cbb + 2.0f * acc4[i][j][r] - nns[j];
          rs += fmaxf(val, 0.0f);
        }
        lsum += mf * rs;
      }
    }
  } else {
    // ortho: sum (gram - I)^2; diagonal computed exactly from f32 fn2
    #pragma unroll
    for (int i = 0; i < 4; ++i) {
      #pragma unroll
      for (int r = 0; r < 4; ++r) {
        int gi = r0 + wy * 64 + i * 16 + (lane >> 4) * 4 + r;
        #pragma unroll
        for (int j = 0; j < 4; ++j) {
          int gj = c0 + wx * 64 + j * 16 + (lane & 15);
          float s = (gi == gj) ? (fn2[gi] - 1.0f) : acc4[i][j][r];
          lsum += s * s;
        }
      }
    }
    lsum *= wgt;
  }

  lsum = wave_reduce_sum(lsum);
  float* red = (float*)smem;
  __syncthreads();
  if (lane == 0) red[wave] = lsum;
  __syncthreads();
  if (tid == 0) {
    float partial = red[0] + red[1] + red[2] + red[3];
    // ordered, fence-free handshake:
    float old = atomicAdd(&acc[seg], partial);
    // consume 'old' -> compiler inserts s_waitcnt vmcnt before the asm, so the
    // acc-add is complete at the coherent point before cnt is bumped.
    asm volatile("" : : "v"(old));
    lastFlag = (atomicAdd(cnt, 1) == (int)gridDim.x - 1) ? 1 : 0;
  }
  __syncthreads();
  if (lastFlag) {
    // all blocks' acc-adds completed before their cnt-adds; we saw the last
    // cnt value, so acc is final. jt/msum came from prep (previous dispatch).
    float sjt = 0.0f, sm = 0.0f;
    for (int i = tid; i < 2048; i += 256) sjt += jt_part[i];
    if (tid < 32) sm = msum_part[tid];
    sjt = wave_reduce_sum(sjt);
    sm = wave_reduce_sum(sm);
    __syncthreads();
    if (lane == 0) { red[wave] = sjt; red[4 + wave] = sm; }
    __syncthreads();
    if (tid == 0) {
      float jt = red[0] + red[1] + red[2] + red[3];
      float ms = red[4] + red[5] + red[6] + red[7];
      float ju = atomicAdd(&acc[0], 0.0f);  // atomic read at coherent point
      float oo = atomicAdd(&acc[1], 0.0f);
      float Ju = (ms == 0.0f) ? 0.0f : ju / ((float)N_N * ms);
      float Jt = (ms == 0.0f) ? 0.0f : jt / ms;
      out[0] = Ju + Jt + 1.0e-3f * oo;
    }
  }
}

extern "C" void kernel_launch(void* const* d_in, const int* in_sizes, int n_in,
                              void* d_out, int out_size, void* d_ws, size_t ws_size,
                              hipStream_t stream) {
  (void)in_sizes; (void)n_in; (void)out_size; (void)ws_size;
  const float* v    = (const float*)d_in[0];
  const float* vhat = (const float*)d_in[1];
  const float* g    = (const float*)d_in[2];
  const float* F    = (const float*)d_in[3];
  const float* neg  = (const float*)d_in[4];
  const int*   mask = (const int*)d_in[5];

  float* ws = (float*)d_ws;
  float* cb        = ws;
  float* nn2       = ws + 8192;
  float* fn2       = ws + 10240;
  float* jt_part   = ws + 10752;
  float* msum_part = ws + 12800;
  float* acc       = ws + 12832;
  int*   cnt       = (int*)(ws + 12834);
  unsigned short* vhat_bf = (unsigned short*)(ws + 12848);
  unsigned short* neg_bf  = vhat_bf + (size_t)B_N * D_N;
  unsigned short* F_bf    = neg_bf + (size_t)N_N * D_N;

  prep_kernel<<<(B_N + N_N + K_N) / 4, 256, 0, stream>>>(
      v, vhat, neg, F, g, mask, vhat_bf, neg_bf, F_bf, cb, nn2, fn2,
      jt_part, msum_part, acc, cnt);
  main_kernel<<<10 + 1024, 256, 0, stream>>>(
      vhat_bf, neg_bf, F_bf, cb, nn2, fn2, mask, jt_part, msum_part,
      acc, cnt, (float*)d_out);
}

// Round 6
// 114.337 us; speedup vs baseline: 1.1615x; 1.1615x over previous
//
#include <hip/hip_runtime.h>

// Problem constants (fixed by reference setup_inputs)
#define B_N 8192
#define D_N 256
#define N_N 2048
#define K_N 512
#define T_N 8

using short8  = __attribute__((ext_vector_type(8))) short;
using floatx4 = __attribute__((ext_vector_type(4))) float;

// ---------------------------------------------------------------------------
// Workspace layout (float units):
//  cb        = ws + 0      [8192]
//  nn2       = ws + 8192   [2048]
//  fn2       = ws + 10240  [512]
//  jt_part   = ws + 10752  [2048]   (per prep-block jt partials)
//  msum_part = ws + 12800  [32]
//  ju_part   = ws + 12832  [1024]
//  or_part   = ws + 13856  [16]
//  vhat_bf   = (ushort*)(ws + 13872)  [8192*256]  (16B aligned: 13872*4%16==0)
//  neg_bf    = vhat_bf + 8192*256     [2048*256]
//  F_bf      = neg_bf + 2048*256      [512*256]
// ---------------------------------------------------------------------------

// butterfly reduce: ALL lanes end with the wave sum
__device__ __forceinline__ float wave_reduce_sum(float x) {
  #pragma unroll
  for (int off = 32; off > 0; off >>= 1) x += __shfl_xor(x, off, 64);
  return x;
}

__device__ __forceinline__ unsigned int f2bf(float x) {
  unsigned u = __float_as_uint(x);
  return (u + 0x7fffu + ((u >> 16) & 1u)) >> 16;
}

__device__ __forceinline__ unsigned int pack2bf(float x, float y) {
  return f2bf(x) | (f2bf(y) << 16);
}

// async global->LDS, 16 bytes per lane; LDS dest is wave-uniform base + lane*16
__device__ __forceinline__ void gload16(const unsigned short* g, unsigned short* l) {
  __builtin_amdgcn_global_load_lds(
      (const __attribute__((address_space(1))) unsigned int*)g,
      (__attribute__((address_space(3))) unsigned int*)l, 16, 0, 0);
}

// compare-swap keeping (val,idx) pairs together
#define CSWAP(a, b)                                              \
  {                                                              \
    bool sw_ = sv[a] > sv[b];                                    \
    float tv_ = sw_ ? sv[a] : sv[b];                             \
    sv[a] = sw_ ? sv[b] : sv[a];                                 \
    sv[b] = tv_;                                                 \
    int ti_ = sw_ ? si[a] : si[b];                               \
    si[a] = sw_ ? si[b] : si[a];                                 \
    si[b] = ti_;                                                 \
  }

// --- prep: stats + bf16 conversion + bottom-8 selection + FUSED jt ----------
// one row per wave; rows [0,B)=vhat(+v,+g-selection,+jt), [B,B+N)=neg, rest=F
__global__ __launch_bounds__(256) void prep_kernel(
    const float* __restrict__ v, const float* __restrict__ vhat,
    const float* __restrict__ neg, const float* __restrict__ F,
    const float* __restrict__ g, const int* __restrict__ mask,
    unsigned short* __restrict__ vhat_bf, unsigned short* __restrict__ neg_bf,
    unsigned short* __restrict__ F_bf,
    float* __restrict__ cb, float* __restrict__ nn2, float* __restrict__ fn2,
    float* __restrict__ jt_part, float* __restrict__ msum_part) {
  int lane = threadIdx.x & 63;
  int wave = threadIdx.x >> 6;
  int row = (blockIdx.x << 2) + wave;
  __shared__ float mred[4];
  __shared__ float jred[4];
  // msum strips: blocks 0..31 each sum 256 mask entries (block-uniform branch)
  if (blockIdx.x < 32) {
    float m = (mask[blockIdx.x * 256 + threadIdx.x] != 0) ? 1.0f : 0.0f;
    m = wave_reduce_sum(m);
    if (lane == 0) mred[wave] = m;
    __syncthreads();
    if (threadIdx.x == 0)
      msum_part[blockIdx.x] = mred[0] + mred[1] + mred[2] + mred[3];
  }
  if (row < B_N) {
    const float4 a = *(const float4*)(vhat + (size_t)row * D_N + lane * 4);
    const float4 b = *(const float4*)(v + (size_t)row * D_N + lane * 4);
    float dx = a.x - b.x, dy = a.y - b.y, dz = a.z - b.z, dw = a.w - b.w;
    float t = dx * dx + dy * dy + dz * dz + dw * dw;
    float n = a.x * a.x + a.y * a.y + a.z * a.z + a.w * a.w;
    uint2 p;
    p.x = pack2bf(a.x, a.y);
    p.y = pack2bf(a.z, a.w);
    *(uint2*)(vhat_bf + (size_t)row * D_N + lane * 4) = p;
    t = wave_reduce_sum(t);  // td, all lanes
    n = wave_reduce_sum(n);  // vn2, all lanes
    if (lane == 0) cb[row] = 1.0f + t - n;
    // ---- bottom-8-of-512 selection on g[row] ----
    const float* grow = g + (size_t)row * K_N;
    float sv[8];
    int si[8];
    {
      float4 g0 = *(const float4*)(grow + lane * 8);
      float4 g1 = *(const float4*)(grow + lane * 8 + 4);
      sv[0] = g0.x; sv[1] = g0.y; sv[2] = g0.z; sv[3] = g0.w;
      sv[4] = g1.x; sv[5] = g1.y; sv[6] = g1.z; sv[7] = g1.w;
      #pragma unroll
      for (int j = 0; j < 8; ++j) si[j] = lane * 8 + j;
    }
    // Batcher odd-even mergesort, n=8 (19 comparators) -> ascending
    CSWAP(0,1) CSWAP(2,3) CSWAP(4,5) CSWAP(6,7)
    CSWAP(0,2) CSWAP(1,3) CSWAP(4,6) CSWAP(5,7)
    CSWAP(1,2) CSWAP(5,6)
    CSWAP(0,4) CSWAP(1,5) CSWAP(2,6) CSWAP(3,7)
    CSWAP(2,4) CSWAP(3,5)
    CSWAP(1,2) CSWAP(3,4) CSWAP(5,6)
    // 6 butterfly merge rounds: keep lowest 8 of (mine ++ partner)
    #pragma unroll
    for (int rr = 0; rr < 6; ++rr) {
      const int msk = 1 << rr;
      float pv[8];
      int pi[8];
      #pragma unroll
      for (int j = 0; j < 8; ++j) {
        pv[j] = __shfl_xor(sv[j], msk, 64);
        pi[j] = __shfl_xor(si[j], msk, 64);
      }
      float cv[8];
      int ci[8];
      #pragma unroll
      for (int j = 0; j < 8; ++j) {
        bool mine = sv[j] <= pv[7 - j];
        cv[j] = mine ? sv[j] : pv[7 - j];
        ci[j] = mine ? si[j] : pi[7 - j];
      }
      #pragma unroll
      for (int j = 0; j < 8; ++j) { sv[j] = cv[j]; si[j] = ci[j]; }
      // bitonic -> sorted (distances 4,2,1)
      CSWAP(0,4) CSWAP(1,5) CSWAP(2,6) CSWAP(3,7)
      CSWAP(0,2) CSWAP(1,3) CSWAP(4,6) CSWAP(5,7)
      CSWAP(0,1) CSWAP(2,3) CSWAP(4,5) CSWAP(6,7)
    }
    // every lane now holds the global bottom-8 (sorted, identical across lanes)
    // ---- fused jt: 8 gathered f32 dot products (F is L2-resident) ----
    float4 fr8[8];
    #pragma unroll
    for (int t8 = 0; t8 < T_N; ++t8) {
      int idx = __builtin_amdgcn_readfirstlane(si[t8]);
      fr8[t8] = *(const float4*)(F + (size_t)idx * D_N + lane * 4);
    }
    float gsum = 1e-10f;
    #pragma unroll
    for (int t8 = 0; t8 < T_N; ++t8) gsum += sv[t8];
    float base = t - n;  // td - vn2, all lanes
    float jts = 0.0f;
    #pragma unroll
    for (int t8 = 0; t8 < T_N; ++t8) {
      float4 f = fr8[t8];
      // s = 2*<vhat,F_idx> - ||F_idx||^2 ; then term = mt + td - vn2 + s
      float s = 2.0f * (a.x * f.x + a.y * f.y + a.z * f.z + a.w * f.w)
              - (f.x * f.x + f.y * f.y + f.z * f.z + f.w * f.w);
      s = wave_reduce_sum(s);
      float gt = sv[t8] / gsum;
      float mt = 1.0f - gt;
      mt *= mt;
      jts += fmaxf(mt + base + s, 0.0f);
    }
    float mf = (mask[row] != 0) ? 1.0f : 0.0f;
    if (lane == 0) jred[wave] = jts * mf;
    __syncthreads();
    if (threadIdx.x == 0)
      jt_part[blockIdx.x] = jred[0] + jred[1] + jred[2] + jred[3];
  } else if (row < B_N + N_N) {
    int r = row - B_N;
    const float4 a = *(const float4*)(neg + (size_t)r * D_N + lane * 4);
    float n = a.x * a.x + a.y * a.y + a.z * a.z + a.w * a.w;
    uint2 p;
    p.x = pack2bf(a.x, a.y);
    p.y = pack2bf(a.z, a.w);
    *(uint2*)(neg_bf + (size_t)r * D_N + lane * 4) = p;
    n = wave_reduce_sum(n);
    if (lane == 0) nn2[r] = n;
  } else {
    int r = row - (B_N + N_N);
    const float4 a = *(const float4*)(F + (size_t)r * D_N + lane * 4);
    float n = a.x * a.x + a.y * a.y + a.z * a.z + a.w * a.w;
    uint2 p;
    p.x = pack2bf(a.x, a.y);
    p.y = pack2bf(a.z, a.w);
    *(uint2*)(F_bf + (size_t)r * D_N + lane * 4) = p;
    n = wave_reduce_sum(n);
    if (lane == 0) fn2[r] = n;
  }
}

// --- main: ortho tiles [0,10) (upper triangle) | ju tiles [10,1034) ---------
// plain partial stores; no atomics/fences (R1/R5 post-mortems: any grid-wide
// last-block handshake costs 15-35 us at ~1k blocks on this chip).
__global__ __launch_bounds__(256) void main_kernel(
    const unsigned short* __restrict__ vhat_bf, const unsigned short* __restrict__ neg_bf,
    const unsigned short* __restrict__ F_bf,
    const float* __restrict__ cb, const float* __restrict__ nn2,
    const float* __restrict__ fn2, const int* __restrict__ mask,
    float* __restrict__ ju_part, float* __restrict__ or_part) {
  __shared__ __align__(16) unsigned char smem[16384];
  const int bx = blockIdx.x;
  const int tid = threadIdx.x;
  const int lane = tid & 63;
  const int wave = tid >> 6;

  unsigned short* AsU = (unsigned short*)smem;  // 128 rows x 32 k (bf16)
  unsigned short* BsU = AsU + 4096;
  int r0, c0, lo = 0;
  const unsigned short *Abase, *Bbase;
  int seg;          // 0=ju 1=ortho
  float wgt = 1.0f;
  if (bx < 10) {
    // ortho first (small); upper-triangle tile (ti<=tj), off-diag counted x2
    seg = 1;
    int o = bx;
    int ti = (o < 4) ? 0 : (o < 7) ? 1 : (o < 9) ? 2 : 3;
    int tj = (o < 4) ? o : (o < 7) ? o - 3 : (o < 9) ? o - 5 : 3;
    r0 = ti * 128;
    c0 = tj * 128;
    wgt = (ti == tj) ? 1.0f : 2.0f;
    Abase = F_bf;
    Bbase = F_bf;
  } else {
    seg = 0;
    int o = bx - 10;
    // XCD swizzle (1024 % 8 == 0, bijective): XCD x owns contiguous lo-range
    // -> 8 consecutive row-panels (0.5 MB A slice) + full neg panel per L2.
    lo = (o & 7) * 128 + (o >> 3);
    r0 = (lo >> 4) * 128;
    c0 = (lo & 15) * 128;
    Abase = vhat_bf;
    Bbase = neg_bf;
  }
  const int wx = wave & 1, wy = wave >> 1;

  // staging: LDS slot (r, c_slot) holds global 16B-chunk c_g = c_slot ^ ((r>>1)&3)
  const int c_slot = lane & 3;
  const int rA0 = wave * 32 + (lane >> 2);
  const int rA1 = rA0 + 16;
  const int cg0 = c_slot ^ ((rA0 >> 1) & 3);
  const int cg1 = c_slot ^ ((rA1 >> 1) & 3);
  const unsigned short* gA0 = Abase + (size_t)(r0 + rA0) * D_N + cg0 * 8;
  const unsigned short* gA1 = Abase + (size_t)(r0 + rA1) * D_N + cg1 * 8;
  const unsigned short* gB0 = Bbase + (size_t)(c0 + rA0) * D_N + cg0 * 8;
  const unsigned short* gB1 = Bbase + (size_t)(c0 + rA1) * D_N + cg1 * 8;
  unsigned short* lA0 = AsU + wave * 1024 + lane * 8;
  unsigned short* lA1 = lA0 + 512;
  unsigned short* lB0 = BsU + wave * 1024 + lane * 8;
  unsigned short* lB1 = lB0 + 512;

  // fragment LDS offsets (constant over k-loop)
  const int fr = lane & 15;
  const int fc = lane >> 4;
  int aoff[4], boff[4];
  #pragma unroll
  for (int i = 0; i < 4; ++i) {
    int ra = wy * 64 + i * 16 + fr;
    aoff[i] = ra * 32 + (fc ^ ((ra >> 1) & 3)) * 8;
    int rb = wx * 64 + i * 16 + fr;
    boff[i] = rb * 32 + (fc ^ ((rb >> 1) & 3)) * 8;
  }

  floatx4 acc4[4][4];
  #pragma unroll
  for (int i = 0; i < 4; ++i)
    #pragma unroll
    for (int j = 0; j < 4; ++j)
      acc4[i][j] = floatx4{0.0f, 0.0f, 0.0f, 0.0f};

  for (int k0 = 0; k0 < D_N; k0 += 32) {
    __syncthreads();
    gload16(gA0 + k0, lA0);
    gload16(gA1 + k0, lA1);
    gload16(gB0 + k0, lB0);
    gload16(gB1 + k0, lB1);
    __syncthreads();
    short8 af[4], bfv[4];
    #pragma unroll
    for (int i = 0; i < 4; ++i) af[i] = *(const short8*)(AsU + aoff[i]);
    #pragma unroll
    for (int j = 0; j < 4; ++j) bfv[j] = *(const short8*)(BsU + boff[j]);
    #pragma unroll
    for (int i = 0; i < 4; ++i)
      #pragma unroll
      for (int j = 0; j < 4; ++j)
        acc4[i][j] = __builtin_amdgcn_mfma_f32_16x16x32_bf16(af[i], bfv[j], acc4[i][j], 0, 0, 0);
  }

  // epilogue: C/D layout col=lane&15 (j), row=(lane>>4)*4+reg (i)
  float lsum = 0.0f;
  if (seg == 0) {
    float nns[4];
    #pragma unroll
    for (int j = 0; j < 4; ++j)
      nns[j] = nn2[c0 + wx * 64 + j * 16 + (lane & 15)];
    #pragma unroll
    for (int i = 0; i < 4; ++i) {
      #pragma unroll
      for (int r = 0; r < 4; ++r) {
        int b = r0 + wy * 64 + i * 16 + (lane >> 4) * 4 + r;
        float cbb = cb[b];
        float mf = (mask[b] != 0) ? 1.0f : 0.0f;
        float rs = 0.0f;
        #pragma unroll
        for (int j = 0; j < 4; ++j) {
          float val = cbb + 2.0f * acc4[i][j][r] - nns[j];
          rs += fmaxf(val, 0.0f);
        }
        lsum += mf * rs;
      }
    }
  } else {
    // ortho: sum (gram - I)^2; diagonal computed exactly from f32 fn2
    #pragma unroll
    for (int i = 0; i < 4; ++i) {
      #pragma unroll
      for (int r = 0; r < 4; ++r) {
        int gi = r0 + wy * 64 + i * 16 + (lane >> 4) * 4 + r;
        #pragma unroll
        for (int j = 0; j < 4; ++j) {
          int gj = c0 + wx * 64 + j * 16 + (lane & 15);
          float s = (gi == gj) ? (fn2[gi] - 1.0f) : acc4[i][j][r];
          lsum += s * s;
        }
      }
    }
    lsum *= wgt;
  }

  lsum = wave_reduce_sum(lsum);
  float* red = (float*)smem;
  __syncthreads();
  if (lane == 0) red[wave] = lsum;
  __syncthreads();
  if (tid == 0) {
    float partial = red[0] + red[1] + red[2] + red[3];
    if (seg == 0) ju_part[lo] = partial;
    else or_part[bx] = partial;
  }
}

// --- finalize: sum small partial arrays, compute output ---------------------
__global__ __launch_bounds__(256) void finalize_kernel(
    const float* __restrict__ jt_part, const float* __restrict__ ju_part,
    const float* __restrict__ or_part, const float* __restrict__ msum_part,
    float* __restrict__ out) {
  int tid = threadIdx.x;
  float sjt = 0.0f, sju = 0.0f, sor = 0.0f, sm = 0.0f;
  for (int i = tid; i < 2048; i += 256) sjt += jt_part[i];
  for (int i = tid; i < 1024; i += 256) sju += ju_part[i];
  if (tid < 10) sor = or_part[tid];
  if (tid < 32) sm = msum_part[tid];
  sjt = wave_reduce_sum(sjt);
  sju = wave_reduce_sum(sju);
  sor = wave_reduce_sum(sor);
  sm  = wave_reduce_sum(sm);
  __shared__ float red[4][4];
  int lane = tid & 63, w = tid >> 6;
  if (lane == 0) {
    red[w][0] = sjt; red[w][1] = sju; red[w][2] = sor; red[w][3] = sm;
  }
  __syncthreads();
  if (tid == 0) {
    float jt = red[0][0] + red[1][0] + red[2][0] + red[3][0];
    float ju = red[0][1] + red[1][1] + red[2][1] + red[3][1];
    float oo = red[0][2] + red[1][2] + red[2][2] + red[3][2];
    float ms = red[0][3] + red[1][3] + red[2][3] + red[3][3];
    float Ju = (ms == 0.0f) ? 0.0f : ju / ((float)N_N * ms);
    float Jt = (ms == 0.0f) ? 0.0f : jt / ms;
    out[0] = Ju + Jt + 1.0e-3f * oo;
  }
}

extern "C" void kernel_launch(void* const* d_in, const int* in_sizes, int n_in,
                              void* d_out, int out_size, void* d_ws, size_t ws_size,
                              hipStream_t stream) {
  (void)in_sizes; (void)n_in; (void)out_size; (void)ws_size;
  const float* v    = (const float*)d_in[0];
  const float* vhat = (const float*)d_in[1];
  const float* g    = (const float*)d_in[2];
  const float* F    = (const float*)d_in[3];
  const float* neg  = (const float*)d_in[4];
  const int*   mask = (const int*)d_in[5];

  float* ws = (float*)d_ws;
  float* cb        = ws;
  float* nn2       = ws + 8192;
  float* fn2       = ws + 10240;
  float* jt_part   = ws + 10752;
  float* msum_part = ws + 12800;
  float* ju_part   = ws + 12832;
  float* or_part   = ws + 13856;
  unsigned short* vhat_bf = (unsigned short*)(ws + 13872);
  unsigned short* neg_bf  = vhat_bf + (size_t)B_N * D_N;
  unsigned short* F_bf    = neg_bf + (size_t)N_N * D_N;

  prep_kernel<<<(B_N + N_N + K_N) / 4, 256, 0, stream>>>(
      v, vhat, neg, F, g, mask, vhat_bf, neg_bf, F_bf, cb, nn2, fn2,
      jt_part, msum_part);
  main_kernel<<<10 + 1024, 256, 0, stream>>>(
      vhat_bf, neg_bf, F_bf, cb, nn2, fn2, mask, ju_part, or_part);
  finalize_kernel<<<1, 256, 0, stream>>>(jt_part, ju_part, or_part, msum_part,
                                         (float*)d_out);
}